// Round 1
// baseline (3317.294 us; speedup 1.0000x reference)
//
#include <hip/hip_runtime.h>
#include <math.h>

#define N_NODES 100000
#define N_EDGES 3200000
#define F_IN    512
#define F1      16
#define F2      40

// ---------------- layer-1 dense matmul: h1 = x @ W1 + b1 ----------------
// thread per (row, j), j in [0,16). Wave = 4 rows x 16 cols; W1 reads are a
// 64B contiguous segment per wave-instruction (L1-resident, 32KB total); x
// reads hit each 128B line 32x from L1.
__global__ void mm1_kernel(const float* __restrict__ x, const float* __restrict__ W1,
                           const float* __restrict__ b1, float* __restrict__ h1) {
    int idx = blockIdx.x * blockDim.x + threadIdx.x;
    if (idx >= N_NODES * F1) return;
    int row = idx >> 4;
    int j   = idx & 15;
    const float* xr = x + (size_t)row * F_IN;
    float s = b1[j];
#pragma unroll 8
    for (int k = 0; k < F_IN; ++k)
        s = fmaf(xr[k], W1[k * F1 + j], s);
    h1[idx] = s;
}

// ---------------- degree: deg[i] = 1 (self loop) + #occurrences in row ----
__global__ void deg_init_kernel(float* __restrict__ deg) {
    int i = blockIdx.x * blockDim.x + threadIdx.x;
    if (i < N_NODES) deg[i] = 1.0f;
}
__global__ void deg_edges_kernel(const int* __restrict__ row, float* __restrict__ deg) {
    int e = blockIdx.x * blockDim.x + threadIdx.x;
    if (e < N_EDGES) unsafeAtomicAdd(&deg[row[e]], 1.0f);
}
__global__ void deg_fin_kernel(float* __restrict__ deg) {
    int i = blockIdx.x * blockDim.x + threadIdx.x;
    if (i < N_NODES) deg[i] = rsqrtf(deg[i]);  // deg -> dis in place
}

// ---------------- self-loop term initializes out1 = dis[i]^2 * h1[i] ------
__global__ void self1_kernel(const float* __restrict__ dis, const float* __restrict__ h1,
                             float* __restrict__ out1) {
    int idx = blockIdx.x * blockDim.x + threadIdx.x;  // over N*4 quads
    if (idx >= N_NODES * 4) return;
    int i = idx >> 2;
    float s = dis[i]; s = s * s;
    float4 v = ((const float4*)h1)[idx];
    v.x *= s; v.y *= s; v.z *= s; v.w *= s;
    ((float4*)out1)[idx] = v;
}

// ---------------- edge aggregation layer 1 (16 wide, 4 threads/edge) ------
__global__ void agg1_kernel(const int* __restrict__ row, const int* __restrict__ col,
                            const float* __restrict__ dis, const float* __restrict__ h1,
                            float* __restrict__ out1) {
    int idx = blockIdx.x * blockDim.x + threadIdx.x;  // over E*4
    if (idx >= N_EDGES * 4) return;
    int e = idx >> 2;
    int q = idx & 3;
    int r = row[e];
    int c = col[e];
    float nrm = dis[r] * dis[c];
    float4 v = ((const float4*)(h1 + (size_t)r * F1))[q];
    float* o = out1 + (size_t)c * F1 + q * 4;
    unsafeAtomicAdd(o + 0, nrm * v.x);
    unsafeAtomicAdd(o + 1, nrm * v.y);
    unsafeAtomicAdd(o + 2, nrm * v.z);
    unsafeAtomicAdd(o + 3, nrm * v.w);
}

// ---------------- layer-2 dense matmul: h2 = relu(out1) @ W2 + b2 ---------
__global__ void mm2_kernel(const float* __restrict__ g1, const float* __restrict__ W2,
                           const float* __restrict__ b2, float* __restrict__ h2) {
    int idx = blockIdx.x * blockDim.x + threadIdx.x;  // over N*40
    if (idx >= N_NODES * F2) return;
    int row = idx / F2;
    int j   = idx - row * F2;
    const float* gr = g1 + (size_t)row * F1;
    float s = b2[j];
#pragma unroll
    for (int k = 0; k < F1; ++k)
        s = fmaf(fmaxf(gr[k], 0.0f), W2[k * F2 + j], s);
    h2[idx] = s;
}

// ---------------- self-loop term initializes out2 = dis[i]^2 * h2[i] ------
__global__ void self2_kernel(const float* __restrict__ dis, const float* __restrict__ h2,
                             float* __restrict__ out2) {
    int idx = blockIdx.x * blockDim.x + threadIdx.x;  // over N*10 quads
    if (idx >= N_NODES * 10) return;
    int i = idx / 10;
    float s = dis[i]; s = s * s;
    float4 v = ((const float4*)h2)[idx];
    v.x *= s; v.y *= s; v.z *= s; v.w *= s;
    ((float4*)out2)[idx] = v;
}

// ---------------- edge aggregation layer 2 (40 wide, 10 threads/edge) -----
__global__ void agg2_kernel(const int* __restrict__ row, const int* __restrict__ col,
                            const float* __restrict__ dis, const float* __restrict__ h2,
                            float* __restrict__ out2) {
    long long idx = (long long)blockIdx.x * blockDim.x + threadIdx.x;  // over E*10
    if (idx >= (long long)N_EDGES * 10) return;
    int e = (int)(idx / 10);
    int q = (int)(idx - (long long)e * 10);
    int r = row[e];
    int c = col[e];
    float nrm = dis[r] * dis[c];
    float4 v = ((const float4*)(h2 + (size_t)r * F2))[q];
    float* o = out2 + (size_t)c * F2 + q * 4;
    unsafeAtomicAdd(o + 0, nrm * v.x);
    unsafeAtomicAdd(o + 1, nrm * v.y);
    unsafeAtomicAdd(o + 2, nrm * v.z);
    unsafeAtomicAdd(o + 3, nrm * v.w);
}

// ---------------- row-wise log_softmax over 40 cols, in place -------------
__global__ void lsm_kernel(float* __restrict__ out) {
    int gid  = blockIdx.x * blockDim.x + threadIdx.x;
    int wave = gid >> 6;
    int lane = threadIdx.x & 63;
    if (wave >= N_NODES) return;
    float v = (lane < F2) ? out[(size_t)wave * F2 + lane] : -INFINITY;
    float m = v;
#pragma unroll
    for (int off = 32; off; off >>= 1)
        m = fmaxf(m, __shfl_xor(m, off, 64));
    float ex = (lane < F2) ? expf(v - m) : 0.0f;
    float ssum = ex;
#pragma unroll
    for (int off = 32; off; off >>= 1)
        ssum += __shfl_xor(ssum, off, 64);
    if (lane < F2) out[(size_t)wave * F2 + lane] = v - m - logf(ssum);
}

extern "C" void kernel_launch(void* const* d_in, const int* in_sizes, int n_in,
                              void* d_out, int out_size, void* d_ws, size_t ws_size,
                              hipStream_t stream) {
    const float* x   = (const float*)d_in[0];
    const int*   ei  = (const int*)d_in[1];
    const float* W1  = (const float*)d_in[2];
    const float* b1  = (const float*)d_in[3];
    const float* W2  = (const float*)d_in[4];
    const float* b2  = (const float*)d_in[5];
    float* out = (float*)d_out;

    const int* row = ei;             // edge_index[0]
    const int* col = ei + N_EDGES;   // edge_index[1]

    // workspace layout (floats): dis | h1 | out1 | h2
    float* dis  = (float*)d_ws;                   // N
    float* h1   = dis + 102400;                   // N*16
    float* out1 = h1  + (size_t)N_NODES * F1;     // N*16
    float* h2   = out1 + (size_t)N_NODES * F1;    // N*40
    // total ~29.2 MB

    const int B = 256;

    // degree / normalization (independent of matmuls)
    deg_init_kernel<<<(N_NODES + B - 1) / B, B, 0, stream>>>(dis);
    deg_edges_kernel<<<(N_EDGES + B - 1) / B, B, 0, stream>>>(row, dis);
    deg_fin_kernel<<<(N_NODES + B - 1) / B, B, 0, stream>>>(dis);

    // layer 1
    mm1_kernel<<<(N_NODES * F1 + B - 1) / B, B, 0, stream>>>(x, W1, b1, h1);
    self1_kernel<<<(N_NODES * 4 + B - 1) / B, B, 0, stream>>>(dis, h1, out1);
    agg1_kernel<<<(N_EDGES * 4 + B - 1) / B, B, 0, stream>>>(row, col, dis, h1, out1);

    // layer 2 (relu fused into mm2)
    mm2_kernel<<<(N_NODES * F2 + B - 1) / B, B, 0, stream>>>(out1, W2, b2, h2);
    self2_kernel<<<(N_NODES * 10 + B - 1) / B, B, 0, stream>>>(dis, h2, out);
    {
        long long total = (long long)N_EDGES * 10;
        int blocks = (int)((total + B - 1) / B);
        agg2_kernel<<<blocks, B, 0, stream>>>(row, col, dis, h2, out);
    }

    // log_softmax in place on d_out
    lsm_kernel<<<(N_NODES * 64 + B - 1) / B, B, 0, stream>>>(out);
}

// Round 2
// 1218.828 us; speedup vs baseline: 2.7217x; 2.7217x over previous
//
#include <hip/hip_runtime.h>
#include <math.h>

#define N_NODES 100000
#define N_EDGES 3200000
#define F_IN    512
#define F1      16
#define F2      40

#define SCAN_TILE 1024   // elements per scan block (256 thr x 4)
#define NBLK ((N_NODES + SCAN_TILE - 1) / SCAN_TILE)   // 98

// ---------------- layer-1 dense matmul: h1 = x @ W1 + b1 ----------------
__global__ void mm1_kernel(const float* __restrict__ x, const float* __restrict__ W1,
                           const float* __restrict__ b1, float* __restrict__ h1) {
    int idx = blockIdx.x * blockDim.x + threadIdx.x;
    if (idx >= N_NODES * F1) return;
    int row = idx >> 4;
    int j   = idx & 15;
    const float* xr = x + (size_t)row * F_IN;
    float s = b1[j];
#pragma unroll 8
    for (int k = 0; k < F_IN; ++k)
        s = fmaf(xr[k], W1[k * F1 + j], s);
    h1[idx] = s;
}

// ---------------- histograms: deg (by row) and col counts ----------------
__global__ void hist_init_kernel(int* __restrict__ deg_i, int* __restrict__ col_cnt) {
    int i = blockIdx.x * blockDim.x + threadIdx.x;
    if (i < N_NODES) { deg_i[i] = 0; col_cnt[i] = 0; }
}
__global__ void hist_kernel(const int* __restrict__ row, const int* __restrict__ col,
                            int* __restrict__ deg_i, int* __restrict__ col_cnt) {
    int e = blockIdx.x * blockDim.x + threadIdx.x;
    if (e >= N_EDGES) return;
    atomicAdd(&deg_i[row[e]], 1);
    atomicAdd(&col_cnt[col[e]], 1);
}
__global__ void deg_fin_kernel(const int* __restrict__ deg_i, float* __restrict__ dis) {
    int i = blockIdx.x * blockDim.x + threadIdx.x;
    if (i < N_NODES) dis[i] = rsqrtf((float)(deg_i[i] + 1));  // +1 self loop
}

// ---------------- exclusive scan of col_cnt -> start (3 kernels) ---------
__global__ void scan1_kernel(const int* __restrict__ cnt, int* __restrict__ start,
                             int* __restrict__ blk_sum) {
    __shared__ int lds[256];
    int tid  = threadIdx.x;
    int base = blockIdx.x * SCAN_TILE + tid * 4;
    int v[4];
    int s = 0;
#pragma unroll
    for (int i = 0; i < 4; ++i) {
        int idx = base + i;
        v[i] = (idx < N_NODES) ? cnt[idx] : 0;
        s += v[i];
    }
    lds[tid] = s;
    __syncthreads();
    // Hillis-Steele inclusive scan over 256 thread sums
    for (int off = 1; off < 256; off <<= 1) {
        int t = (tid >= off) ? lds[tid - off] : 0;
        __syncthreads();
        lds[tid] += t;
        __syncthreads();
    }
    int excl = lds[tid] - s;  // exclusive prefix within block
    int run = excl;
#pragma unroll
    for (int i = 0; i < 4; ++i) {
        int idx = base + i;
        if (idx < N_NODES) start[idx] = run;
        run += v[i];
    }
    if (tid == 255) blk_sum[blockIdx.x] = lds[255];
}

__global__ void scan2_kernel(const int* __restrict__ blk_sum, int* __restrict__ blk_off) {
    __shared__ int lds[128];
    int tid = threadIdx.x;  // single block of 128
    int s = (tid < NBLK) ? blk_sum[tid] : 0;
    lds[tid] = s;
    __syncthreads();
    for (int off = 1; off < 128; off <<= 1) {
        int t = (tid >= off) ? lds[tid - off] : 0;
        __syncthreads();
        lds[tid] += t;
        __syncthreads();
    }
    if (tid < NBLK) blk_off[tid] = lds[tid] - s;
}

__global__ void scan3_kernel(int* __restrict__ start, const int* __restrict__ blk_off,
                             int* __restrict__ cursor) {
    int i = blockIdx.x * blockDim.x + threadIdx.x;
    if (i >= N_NODES) return;
    int s = start[i] + blk_off[i >> 10];
    start[i]  = s;
    cursor[i] = s;
}

// ---------------- bucket edges by col: rows_sorted -----------------------
__global__ void scatter_kernel(const int* __restrict__ row, const int* __restrict__ col,
                               int* __restrict__ cursor, int* __restrict__ rows_sorted) {
    int e = blockIdx.x * blockDim.x + threadIdx.x;
    if (e >= N_EDGES) return;
    int pos = atomicAdd(&cursor[col[e]], 1);
    rows_sorted[pos] = row[e];
}

// ---------------- layer-1 aggregation via gather (4 thr/node) ------------
__global__ void agg1_gather_kernel(const int* __restrict__ rows_sorted,
                                   const int* __restrict__ start, const int* __restrict__ cnt,
                                   const float* __restrict__ dis, const float* __restrict__ h1,
                                   float* __restrict__ out1) {
    int idx = blockIdx.x * blockDim.x + threadIdx.x;
    if (idx >= N_NODES * 4) return;
    int c = idx >> 2;
    int q = idx & 3;
    float dc = dis[c];
    const float4* h4 = (const float4*)h1;
    float4 acc = h4[(size_t)c * 4 + q];         // self loop: dc * h1[c], * dc at end
    acc.x *= dc; acc.y *= dc; acc.z *= dc; acc.w *= dc;
    int k0 = start[c];
    int k1 = k0 + cnt[c];
    for (int k = k0; k < k1; ++k) {
        int r = rows_sorted[k];
        float s = dis[r];
        float4 v = h4[(size_t)r * 4 + q];
        acc.x = fmaf(s, v.x, acc.x);
        acc.y = fmaf(s, v.y, acc.y);
        acc.z = fmaf(s, v.z, acc.z);
        acc.w = fmaf(s, v.w, acc.w);
    }
    acc.x *= dc; acc.y *= dc; acc.z *= dc; acc.w *= dc;
    ((float4*)out1)[(size_t)c * 4 + q] = acc;
}

// ---------------- layer-2 dense matmul: h2 = relu(out1) @ W2 + b2 --------
__global__ void mm2_kernel(const float* __restrict__ g1, const float* __restrict__ W2,
                           const float* __restrict__ b2, float* __restrict__ h2) {
    int idx = blockIdx.x * blockDim.x + threadIdx.x;
    if (idx >= N_NODES * F2) return;
    int row = idx / F2;
    int j   = idx - row * F2;
    const float* gr = g1 + (size_t)row * F1;
    float s = b2[j];
#pragma unroll
    for (int k = 0; k < F1; ++k)
        s = fmaf(fmaxf(gr[k], 0.0f), W2[k * F2 + j], s);
    h2[idx] = s;
}

// ---------------- layer-2 aggregation via gather (10 thr/node) -----------
__global__ void agg2_gather_kernel(const int* __restrict__ rows_sorted,
                                   const int* __restrict__ start, const int* __restrict__ cnt,
                                   const float* __restrict__ dis, const float* __restrict__ h2,
                                   float* __restrict__ out2) {
    int idx = blockIdx.x * blockDim.x + threadIdx.x;
    if (idx >= N_NODES * 10) return;
    int c = idx / 10;
    int q = idx - c * 10;
    float dc = dis[c];
    const float4* h4 = (const float4*)h2;
    float4 acc = h4[(size_t)c * 10 + q];
    acc.x *= dc; acc.y *= dc; acc.z *= dc; acc.w *= dc;
    int k0 = start[c];
    int k1 = k0 + cnt[c];
    for (int k = k0; k < k1; ++k) {
        int r = rows_sorted[k];
        float s = dis[r];
        float4 v = h4[(size_t)r * 10 + q];
        acc.x = fmaf(s, v.x, acc.x);
        acc.y = fmaf(s, v.y, acc.y);
        acc.z = fmaf(s, v.z, acc.z);
        acc.w = fmaf(s, v.w, acc.w);
    }
    acc.x *= dc; acc.y *= dc; acc.z *= dc; acc.w *= dc;
    ((float4*)out2)[(size_t)c * 10 + q] = acc;
}

// ---------------- row-wise log_softmax over 40 cols, in place ------------
__global__ void lsm_kernel(float* __restrict__ out) {
    int gid  = blockIdx.x * blockDim.x + threadIdx.x;
    int wave = gid >> 6;
    int lane = threadIdx.x & 63;
    if (wave >= N_NODES) return;
    float v = (lane < F2) ? out[(size_t)wave * F2 + lane] : -INFINITY;
    float m = v;
#pragma unroll
    for (int off = 32; off; off >>= 1)
        m = fmaxf(m, __shfl_xor(m, off, 64));
    float ex = (lane < F2) ? expf(v - m) : 0.0f;
    float ssum = ex;
#pragma unroll
    for (int off = 32; off; off >>= 1)
        ssum += __shfl_xor(ssum, off, 64);
    if (lane < F2) out[(size_t)wave * F2 + lane] = v - m - logf(ssum);
}

extern "C" void kernel_launch(void* const* d_in, const int* in_sizes, int n_in,
                              void* d_out, int out_size, void* d_ws, size_t ws_size,
                              hipStream_t stream) {
    const float* x   = (const float*)d_in[0];
    const int*   ei  = (const int*)d_in[1];
    const float* W1  = (const float*)d_in[2];
    const float* b1  = (const float*)d_in[3];
    const float* W2  = (const float*)d_in[4];
    const float* b2  = (const float*)d_in[5];
    float* out = (float*)d_out;

    const int* row = ei;             // edge_index[0]
    const int* col = ei + N_EDGES;   // edge_index[1]

    // workspace layout (element offsets; ~43.7 MB total)
    float* fws  = (float*)d_ws;
    float* dis  = fws;                                   // 102400 pad
    float* h1   = dis + 102400;                          // N*16
    float* out1 = h1  + (size_t)N_NODES * F1;            // N*16
    float* h2   = out1 + (size_t)N_NODES * F1;           // N*40
    int*   iws  = (int*)(h2 + (size_t)N_NODES * F2);
    int* deg_i       = iws;                              // 102400
    int* col_cnt     = deg_i + 102400;                   // 102400
    int* start       = col_cnt + 102400;                 // 102400
    int* cursor      = start + 102400;                   // 102400
    int* blk_sum     = cursor + 102400;                  // 1024
    int* blk_off     = blk_sum + 1024;                   // 1024
    int* rows_sorted = blk_off + 1024;                   // N_EDGES

    const int B = 256;
    const int gridN = (N_NODES + B - 1) / B;
    const int gridE = (N_EDGES + B - 1) / B;

    // ---- build normalization + CSR-by-col (independent of matmuls) ----
    hist_init_kernel<<<gridN, B, 0, stream>>>(deg_i, col_cnt);
    hist_kernel<<<gridE, B, 0, stream>>>(row, col, deg_i, col_cnt);
    deg_fin_kernel<<<gridN, B, 0, stream>>>(deg_i, dis);
    scan1_kernel<<<NBLK, 256, 0, stream>>>(col_cnt, start, blk_sum);
    scan2_kernel<<<1, 128, 0, stream>>>(blk_sum, blk_off);
    scan3_kernel<<<gridN, B, 0, stream>>>(start, blk_off, cursor);
    scatter_kernel<<<gridE, B, 0, stream>>>(row, col, cursor, rows_sorted);

    // ---- layer 1 ----
    mm1_kernel<<<(N_NODES * F1 + B - 1) / B, B, 0, stream>>>(x, W1, b1, h1);
    agg1_gather_kernel<<<(N_NODES * 4 + B - 1) / B, B, 0, stream>>>(
        rows_sorted, start, col_cnt, dis, h1, out1);

    // ---- layer 2 (relu fused into mm2) ----
    mm2_kernel<<<(N_NODES * F2 + B - 1) / B, B, 0, stream>>>(out1, W2, b2, h2);
    agg2_gather_kernel<<<(N_NODES * 10 + B - 1) / B, B, 0, stream>>>(
        rows_sorted, start, col_cnt, dis, h2, out);

    // ---- log_softmax in place on d_out ----
    lsm_kernel<<<(N_NODES * 64 + B - 1) / B, B, 0, stream>>>(out);
}

// Round 3
// 1121.841 us; speedup vs baseline: 2.9570x; 1.0865x over previous
//
#include <hip/hip_runtime.h>
#include <math.h>

#define N_NODES 100000
#define N_EDGES 3200000
#define F_IN    512
#define F1      16
#define F2      40

#define N_BUCKETS 6250               // col >> 4 : 16 cols per bucket
#define SCAN_TILE 1024               // elements per scan block (256 thr x 4)
#define NBLK ((N_NODES + SCAN_TILE - 1) / SCAN_TILE)   // 98

// ---------------- layer-1 dense matmul: h1 = x @ W1 + b1 ----------------
__global__ void mm1_kernel(const float* __restrict__ x, const float* __restrict__ W1,
                           const float* __restrict__ b1, float* __restrict__ h1) {
    int idx = blockIdx.x * blockDim.x + threadIdx.x;
    if (idx >= N_NODES * F1) return;
    int row = idx >> 4;
    int j   = idx & 15;
    const float* xr = x + (size_t)row * F_IN;
    float s = b1[j];
#pragma unroll 8
    for (int k = 0; k < F_IN; ++k)
        s = fmaf(xr[k], W1[k * F1 + j], s);
    h1[idx] = s;
}

// ---------------- histograms: deg (by row) and col counts ----------------
__global__ void hist_init_kernel(int* __restrict__ deg_i, int* __restrict__ col_cnt) {
    int i = blockIdx.x * blockDim.x + threadIdx.x;
    if (i < N_NODES) { deg_i[i] = 0; col_cnt[i] = 0; }
}
__global__ void hist_kernel(const int* __restrict__ row, const int* __restrict__ col,
                            int* __restrict__ deg_i, int* __restrict__ col_cnt) {
    int e = blockIdx.x * blockDim.x + threadIdx.x;
    if (e >= N_EDGES) return;
    atomicAdd(&deg_i[row[e]], 1);
    atomicAdd(&col_cnt[col[e]], 1);
}
__global__ void deg_fin_kernel(const int* __restrict__ deg_i, float* __restrict__ dis) {
    int i = blockIdx.x * blockDim.x + threadIdx.x;
    if (i < N_NODES) dis[i] = rsqrtf((float)(deg_i[i] + 1));  // +1 self loop
}

// ---------------- exclusive scan of col_cnt -> start (3 kernels) ---------
__global__ void scan1_kernel(const int* __restrict__ cnt, int* __restrict__ start,
                             int* __restrict__ blk_sum) {
    __shared__ int lds[256];
    int tid  = threadIdx.x;
    int base = blockIdx.x * SCAN_TILE + tid * 4;
    int v[4];
    int s = 0;
#pragma unroll
    for (int i = 0; i < 4; ++i) {
        int idx = base + i;
        v[i] = (idx < N_NODES) ? cnt[idx] : 0;
        s += v[i];
    }
    lds[tid] = s;
    __syncthreads();
    for (int off = 1; off < 256; off <<= 1) {
        int t = (tid >= off) ? lds[tid - off] : 0;
        __syncthreads();
        lds[tid] += t;
        __syncthreads();
    }
    int excl = lds[tid] - s;
    int run = excl;
#pragma unroll
    for (int i = 0; i < 4; ++i) {
        int idx = base + i;
        if (idx < N_NODES) start[idx] = run;
        run += v[i];
    }
    if (tid == 255) blk_sum[blockIdx.x] = lds[255];
}

__global__ void scan2_kernel(const int* __restrict__ blk_sum, int* __restrict__ blk_off) {
    __shared__ int lds[128];
    int tid = threadIdx.x;  // single block of 128
    int s = (tid < NBLK) ? blk_sum[tid] : 0;
    lds[tid] = s;
    __syncthreads();
    for (int off = 1; off < 128; off <<= 1) {
        int t = (tid >= off) ? lds[tid - off] : 0;
        __syncthreads();
        lds[tid] += t;
        __syncthreads();
    }
    if (tid < NBLK) blk_off[tid] = lds[tid] - s;
}

__global__ void scan3_kernel(int* __restrict__ start, const int* __restrict__ blk_off,
                             int* __restrict__ cursor) {
    int i = blockIdx.x * blockDim.x + threadIdx.x;
    if (i >= N_NODES) return;
    int s = start[i] + blk_off[i >> 10];
    start[i]  = s;
    cursor[i] = s;
}

__global__ void bcur_init_kernel(const int* __restrict__ start, int* __restrict__ bcur) {
    int b = blockIdx.x * blockDim.x + threadIdx.x;
    if (b < N_BUCKETS) bcur[b] = start[b << 4];
}

// ---- scatter pass 1: coarse-bin (row | low4(col)) by col>>4 -------------
// Appends to a bucket land at consecutive addresses -> lines fill fully.
__global__ void scatter_p1_kernel(const int* __restrict__ row, const int* __restrict__ col,
                                  int* __restrict__ bcur, int* __restrict__ pairs) {
    int e = blockIdx.x * blockDim.x + threadIdx.x;
    if (e >= N_EDGES) return;
    int r = row[e];
    int c = col[e];
    int pos = atomicAdd(&bcur[c >> 4], 1);
    pairs[pos] = r | ((c & 15) << 27);
}

// ---- scatter pass 2: bucket -> exact CSR slot; dest window ~2KB/block ----
__global__ void scatter_p2_kernel(const int* __restrict__ pairs, const int* __restrict__ start,
                                  int* __restrict__ cursor, int* __restrict__ rows_sorted) {
    int b = blockIdx.x;
    int beg = start[b << 4];
    int end = (b == N_BUCKETS - 1) ? N_EDGES : start[(b + 1) << 4];
    for (int k = beg + threadIdx.x; k < end; k += 256) {
        unsigned e = (unsigned)pairs[k];
        int r = (int)(e & 0x07FFFFFFu);
        int c = (b << 4) | (int)(e >> 27);
        int pos = atomicAdd(&cursor[c], 1);
        rows_sorted[pos] = r;
    }
}

// ---------------- layer-1 aggregation + relu + row-sum s (4 thr/node) ----
__global__ void agg1_kernel(const int* __restrict__ rows_sorted,
                            const int* __restrict__ start, const int* __restrict__ cnt,
                            const float* __restrict__ dis, const float* __restrict__ h1,
                            float* __restrict__ g, float* __restrict__ s_out) {
    int idx = blockIdx.x * blockDim.x + threadIdx.x;
    if (idx >= N_NODES * 4) return;
    int c = idx >> 2;
    int q = idx & 3;
    float dc = dis[c];
    const float4* h4 = (const float4*)h1;
    float4 acc = h4[(size_t)c * 4 + q];          // self loop
    acc.x *= dc; acc.y *= dc; acc.z *= dc; acc.w *= dc;
    float ss = dc;
    int k0 = start[c];
    int k1 = k0 + cnt[c];
    for (int k = k0; k < k1; ++k) {
        int r = rows_sorted[k];
        float dr = dis[r];
        ss += dr;
        float4 v = h4[(size_t)r * 4 + q];
        acc.x = fmaf(dr, v.x, acc.x);
        acc.y = fmaf(dr, v.y, acc.y);
        acc.z = fmaf(dr, v.z, acc.z);
        acc.w = fmaf(dr, v.w, acc.w);
    }
    acc.x = fmaxf(acc.x * dc, 0.0f);   // relu fused
    acc.y = fmaxf(acc.y * dc, 0.0f);
    acc.z = fmaxf(acc.z * dc, 0.0f);
    acc.w = fmaxf(acc.w * dc, 0.0f);
    ((float4*)g)[(size_t)c * 4 + q] = acc;
    if (q == 0) s_out[c] = dc * ss;    // s = (A_hat . 1)[c], for commuted b2
}

// ---------------- layer-2 aggregation in 16-dim: t = A_hat . g -----------
__global__ void agg2_kernel(const int* __restrict__ rows_sorted,
                            const int* __restrict__ start, const int* __restrict__ cnt,
                            const float* __restrict__ dis, const float* __restrict__ g,
                            float* __restrict__ t) {
    int idx = blockIdx.x * blockDim.x + threadIdx.x;
    if (idx >= N_NODES * 4) return;
    int c = idx >> 2;
    int q = idx & 3;
    float dc = dis[c];
    const float4* h4 = (const float4*)g;
    float4 acc = h4[(size_t)c * 4 + q];
    acc.x *= dc; acc.y *= dc; acc.z *= dc; acc.w *= dc;
    int k0 = start[c];
    int k1 = k0 + cnt[c];
    for (int k = k0; k < k1; ++k) {
        int r = rows_sorted[k];
        float dr = dis[r];
        float4 v = h4[(size_t)r * 4 + q];
        acc.x = fmaf(dr, v.x, acc.x);
        acc.y = fmaf(dr, v.y, acc.y);
        acc.z = fmaf(dr, v.z, acc.z);
        acc.w = fmaf(dr, v.w, acc.w);
    }
    acc.x *= dc; acc.y *= dc; acc.z *= dc; acc.w *= dc;
    ((float4*)t)[(size_t)c * 4 + q] = acc;
}

// ------- fused: out = log_softmax(t @ W2 + s*b2^T), wave per node ---------
__global__ void mm2lsm_kernel(const float* __restrict__ t, const float* __restrict__ s,
                              const float* __restrict__ W2, const float* __restrict__ b2,
                              float* __restrict__ out) {
    __shared__ float w2s[F1 * F2];   // 640
    __shared__ float b2s[F2];
    __shared__ float ts[4 * F1];     // 4 nodes x 16
    int tid = threadIdx.x;
    for (int i = tid; i < F1 * F2; i += 256) w2s[i] = W2[i];
    if (tid < F2) b2s[tid] = b2[tid];
    int nodeBase = blockIdx.x * 4;
    if (tid < 4 * F1) ts[tid] = t[(size_t)nodeBase * F1 + tid];
    __syncthreads();
    int w    = tid >> 6;
    int lane = tid & 63;
    int c = nodeBase + w;
    float sc = s[c];
    float v = -INFINITY;
    if (lane < F2) {
        float acc = sc * b2s[lane];
#pragma unroll
        for (int k = 0; k < F1; ++k)
            acc = fmaf(ts[w * F1 + k], w2s[k * F2 + lane], acc);
        v = acc;
    }
    float m = v;
#pragma unroll
    for (int off = 32; off; off >>= 1)
        m = fmaxf(m, __shfl_xor(m, off, 64));
    float ex = (lane < F2) ? expf(v - m) : 0.0f;
    float ssum = ex;
#pragma unroll
    for (int off = 32; off; off >>= 1)
        ssum += __shfl_xor(ssum, off, 64);
    if (lane < F2) out[(size_t)c * F2 + lane] = v - m - logf(ssum);
}

extern "C" void kernel_launch(void* const* d_in, const int* in_sizes, int n_in,
                              void* d_out, int out_size, void* d_ws, size_t ws_size,
                              hipStream_t stream) {
    const float* x   = (const float*)d_in[0];
    const int*   ei  = (const int*)d_in[1];
    const float* W1  = (const float*)d_in[2];
    const float* b1  = (const float*)d_in[3];
    const float* W2  = (const float*)d_in[4];
    const float* b2  = (const float*)d_in[5];
    float* out = (float*)d_out;

    const int* row = ei;             // edge_index[0]
    const int* col = ei + N_EDGES;   // edge_index[1]

    // workspace layout, 4B units, P = 102400 quantum (~41.2 MB total)
    const size_t P = 102400;
    float* fws  = (float*)d_ws;
    float* dis  = fws;               // P
    float* s    = dis + P;           // P
    float* g    = s + P;             // 16P
    float* t    = g + 16 * P;        // 16P
    int* iws    = (int*)(t + 16 * P);
    int* deg_i       = iws;          // P
    int* col_cnt     = deg_i + P;    // P
    int* start       = col_cnt + P;  // P
    int* cursor      = start + P;    // P
    int* bcur        = cursor + P;   // 8192 (padded)
    int* blk_sum     = bcur + 8192;  // 1024
    int* blk_off     = blk_sum + 1024;   // 1024
    int* pairs       = blk_off + 1024;   // N_EDGES (dead after p2)
    int* rows_sorted = pairs + N_EDGES;  // N_EDGES
    float* h1 = (float*)pairs;       // alias: mm1 runs after scatter_p2

    const int B = 256;
    const int gridN = (N_NODES + B - 1) / B;
    const int gridE = (N_EDGES + B - 1) / B;

    // ---- graph build: normalization + CSR-by-col via 2-phase scatter ----
    hist_init_kernel<<<gridN, B, 0, stream>>>(deg_i, col_cnt);
    hist_kernel<<<gridE, B, 0, stream>>>(row, col, deg_i, col_cnt);
    deg_fin_kernel<<<gridN, B, 0, stream>>>(deg_i, dis);
    scan1_kernel<<<NBLK, 256, 0, stream>>>(col_cnt, start, blk_sum);
    scan2_kernel<<<1, 128, 0, stream>>>(blk_sum, blk_off);
    scan3_kernel<<<gridN, B, 0, stream>>>(start, blk_off, cursor);
    bcur_init_kernel<<<(N_BUCKETS + B - 1) / B, B, 0, stream>>>(start, bcur);
    scatter_p1_kernel<<<gridE, B, 0, stream>>>(row, col, bcur, pairs);
    scatter_p2_kernel<<<N_BUCKETS, B, 0, stream>>>(pairs, start, cursor, rows_sorted);

    // ---- layer 1: h1 = x@W1+b1 ; g = relu(A_hat h1) ; s = A_hat 1 ----
    mm1_kernel<<<(N_NODES * F1 + B - 1) / B, B, 0, stream>>>(x, W1, b1, h1);
    agg1_kernel<<<(N_NODES * 4 + B - 1) / B, B, 0, stream>>>(
        rows_sorted, start, col_cnt, dis, h1, g, s);

    // ---- layer 2 (W2 commuted past aggregation): t = A_hat g ----
    agg2_kernel<<<(N_NODES * 4 + B - 1) / B, B, 0, stream>>>(
        rows_sorted, start, col_cnt, dis, g, t);

    // ---- out = log_softmax(t@W2 + s*b2) ----
    mm2lsm_kernel<<<N_NODES / 4, B, 0, stream>>>(t, s, W2, b2, out);
}